// Round 1
// baseline (1186.937 us; speedup 1.0000x reference)
//
#include <hip/hip_runtime.h>

// ---------------------------------------------------------------------------
// MultiHeadVisionAttention: B=32, N=1024, H=1024, NH=16, D=64
//   q = head(query @ Wq.T); k = head(key @ Wk.T); v = head(value @ Wv.T)
//   attn = softmax_e( (q^T (k+pe)) / 8 )           [per head: 64x64, K=1024]
//   out  = (v @ attn^T) -> [B,N,H] @ Wo.T
// Round 1: correctness-first. 4x bf16 MFMA GEMM (128x128 tile, m92-class),
// fused attn kernel (1 block / head).
// ---------------------------------------------------------------------------

typedef __bf16 bf16x8 __attribute__((ext_vector_type(8)));
typedef __bf16 bf16x4 __attribute__((ext_vector_type(4)));
typedef float  f32x4  __attribute__((ext_vector_type(4)));

__device__ __forceinline__ bf16x8 pack_bf16x8(const float4& lo, const float4& hi) {
  bf16x8 t;
  t[0] = (__bf16)lo.x; t[1] = (__bf16)lo.y; t[2] = (__bf16)lo.z; t[3] = (__bf16)lo.w;
  t[4] = (__bf16)hi.x; t[5] = (__bf16)hi.y; t[6] = (__bf16)hi.z; t[7] = (__bf16)hi.w;
  return t;
}

// C[M,N] = A[M,K] @ B[N,K]^T (+ optional positional-encoding add on C cols%64)
// 256 threads = 4 waves (2x2), each wave owns a 64x64 sub-tile = 4x4 MFMA frags.
// BK=32, single-buffered LDS, mfma_f32_16x16x32_bf16, f32 accumulate.
template<bool A_IS_F32, bool OUT_BF16, bool ADD_PE>
__global__ __launch_bounds__(256)
void gemm_bt(const void* __restrict__ Av, const float* __restrict__ B,
             void* __restrict__ Cv, const float* __restrict__ pe,
             int M, int N, int K)
{
  __shared__ __bf16 As[128][32];
  __shared__ __bf16 Bs[128][32];

  const int tid  = threadIdx.x;
  const int lane = tid & 63;
  const int wave = tid >> 6;
  const int wm = wave >> 1, wn = wave & 1;
  const int lr = lane & 15, lk = lane >> 4;

  const int  nb  = N >> 7;
  const int  bx  = blockIdx.x % nb;
  const int  by  = blockIdx.x / nb;
  const long am0 = (long)by << 7;   // tile row origin
  const long bn0 = (long)bx << 7;   // tile col origin

  f32x4 acc[4][4] = {};

  const int sr4  = tid >> 2, sc8  = (tid & 3) << 3;  // f32 staging: row, col8
  const int sr2  = tid >> 1, sc16 = (tid & 1) << 4;  // bf16 staging: row, col16

  for (int k0 = 0; k0 < K; k0 += 32) {
    float4 a0, a1, a2, a3, b0, b1, b2, b3;
    bf16x8 ab0, ab1;
    if constexpr (A_IS_F32) {
      const float* A  = (const float*)Av;
      const float* p0 = A + (am0 + sr4) * K + (k0 + sc8);
      const float* p1 = p0 + (long)64 * K;
      a0 = *(const float4*)p0; a1 = *(const float4*)(p0 + 4);
      a2 = *(const float4*)p1; a3 = *(const float4*)(p1 + 4);
    } else {
      const __bf16* A  = (const __bf16*)Av;
      const __bf16* p0 = A + (am0 + sr2) * K + (k0 + sc16);
      ab0 = *(const bf16x8*)p0;
      ab1 = *(const bf16x8*)(p0 + 8);
    }
    {
      const float* p0 = B + (bn0 + sr4) * K + (k0 + sc8);
      const float* p1 = p0 + (long)64 * K;
      b0 = *(const float4*)p0; b1 = *(const float4*)(p0 + 4);
      b2 = *(const float4*)p1; b3 = *(const float4*)(p1 + 4);
    }
    __syncthreads();   // previous iteration's fragment reads complete
    if constexpr (A_IS_F32) {
      *(bf16x8*)&As[sr4     ][sc8] = pack_bf16x8(a0, a1);
      *(bf16x8*)&As[sr4 + 64][sc8] = pack_bf16x8(a2, a3);
    } else {
      *(bf16x8*)&As[sr2][sc16    ] = ab0;
      *(bf16x8*)&As[sr2][sc16 + 8] = ab1;
    }
    *(bf16x8*)&Bs[sr4     ][sc8] = pack_bf16x8(b0, b1);
    *(bf16x8*)&Bs[sr4 + 64][sc8] = pack_bf16x8(b2, b3);
    __syncthreads();

    bf16x8 af[4], bfv[4];
    #pragma unroll
    for (int i = 0; i < 4; ++i)
      af[i] = *(const bf16x8*)&As[(wm << 6) + (i << 4) + lr][lk << 3];
    #pragma unroll
    for (int j = 0; j < 4; ++j)
      bfv[j] = *(const bf16x8*)&Bs[(wn << 6) + (j << 4) + lr][lk << 3];
    #pragma unroll
    for (int i = 0; i < 4; ++i)
      #pragma unroll
      for (int j = 0; j < 4; ++j)
        acc[i][j] = __builtin_amdgcn_mfma_f32_16x16x32_bf16(af[i], bfv[j], acc[i][j], 0, 0, 0);
  }

  // Epilogue: D layout col=lane&15, row=(lane>>4)*4+reg  [m89-verified]
  #pragma unroll
  for (int i = 0; i < 4; ++i) {
    #pragma unroll
    for (int j = 0; j < 4; ++j) {
      const int col = (int)bn0 + (wn << 6) + (j << 4) + lr;
      #pragma unroll
      for (int r = 0; r < 4; ++r) {
        const long row = am0 + (wm << 6) + (i << 4) + (lk << 2) + r;
        float v = acc[i][j][r];
        if constexpr (ADD_PE)
          v += pe[((row & 1023) << 6) + (col & 63)];   // pe[n, e], n=row%1024, e=col%64
        if constexpr (OUT_BF16)
          ((__bf16*)Cv)[row * (long)N + col] = (__bf16)v;
        else
          ((float*)Cv)[row * (long)N + col] = v;
      }
    }
  }
}

// One block (256 thr) per head (bh = b*16+h). Computes the 64x64 score matrix
// over K=n=1024, softmax over e, then out_pre[n,d] = sum_e attn[d,e] v[n,e].
__global__ __launch_bounds__(256)
void attn_out_kernel(const __bf16* __restrict__ Q, const __bf16* __restrict__ Kp,
                     const __bf16* __restrict__ V, __bf16* __restrict__ OP)
{
  __shared__ float Qs[64][68];   // +4 pad: conflict-free f32x4 reads
  __shared__ float Ks[64][68];
  __shared__ float At[64][68];
  __shared__ float Vs[16][64];

  const int    tid  = threadIdx.x;
  const int    bh   = blockIdx.x;
  const size_t base = ((size_t)(bh >> 4) << 20) + (size_t)((bh & 15) << 6); // b*N*H + h*64

  const int tx = tid & 15, ty = tid >> 4;          // thread owns d=ty*4+i, e=tx*4+j
  const int lrow = tid >> 2, lcs = (tid & 3) << 4; // staging map: 16 elems/thread

  float c[4][4] = {};

  for (int n0 = 0; n0 < 1024; n0 += 64) {
    const __bf16* qp = Q  + base + (size_t)(n0 + lrow) * 1024 + lcs;
    const __bf16* kp = Kp + base + (size_t)(n0 + lrow) * 1024 + lcs;
    bf16x8 q0 = *(const bf16x8*)qp;
    bf16x8 q1 = *(const bf16x8*)(qp + 8);
    bf16x8 k0 = *(const bf16x8*)kp;
    bf16x8 k1 = *(const bf16x8*)(kp + 8);
    __syncthreads();
    #pragma unroll
    for (int e = 0; e < 8; ++e) {
      Qs[lrow][lcs + e]     = (float)q0[e];
      Qs[lrow][lcs + 8 + e] = (float)q1[e];
      Ks[lrow][lcs + e]     = (float)k0[e];
      Ks[lrow][lcs + 8 + e] = (float)k1[e];
    }
    __syncthreads();
    #pragma unroll 4
    for (int n = 0; n < 64; ++n) {
      f32x4 qv = *(const f32x4*)&Qs[n][ty << 2];
      f32x4 kv = *(const f32x4*)&Ks[n][tx << 2];
      #pragma unroll
      for (int i = 0; i < 4; ++i)
        #pragma unroll
        for (int j = 0; j < 4; ++j)
          c[i][j] += qv[i] * kv[j];
    }
  }

  // softmax over e for rows d=ty*4+i; row spread over 16 consecutive lanes (tx)
  const float scale = 0.125f;   // 1/sqrt(64)
  #pragma unroll
  for (int i = 0; i < 4; ++i) {
    float mi = fmaxf(fmaxf(c[i][0], c[i][1]), fmaxf(c[i][2], c[i][3]));
    #pragma unroll
    for (int s = 1; s < 16; s <<= 1) mi = fmaxf(mi, __shfl_xor(mi, s, 64));
    float p[4], sum = 0.f;
    #pragma unroll
    for (int j = 0; j < 4; ++j) { p[j] = __expf((c[i][j] - mi) * scale); sum += p[j]; }
    #pragma unroll
    for (int s = 1; s < 16; s <<= 1) sum += __shfl_xor(sum, s, 64);
    const float inv = 1.0f / sum;
    f32x4 pv; pv[0] = p[0]*inv; pv[1] = p[1]*inv; pv[2] = p[2]*inv; pv[3] = p[3]*inv;
    *(f32x4*)&At[(ty << 2) + i][tx << 2] = pv;
  }
  __syncthreads();

  // each thread keeps its attn row in registers (statically indexed)
  const int d  = tid & 63;
  const int nq = tid >> 6;
  float ar[64];
  #pragma unroll
  for (int e4 = 0; e4 < 16; ++e4) {
    f32x4 t = *(const f32x4*)&At[d][e4 << 2];
    ar[e4*4+0] = t[0]; ar[e4*4+1] = t[1]; ar[e4*4+2] = t[2]; ar[e4*4+3] = t[3];
  }

  const int vrow = tid >> 4, vcs = (tid & 15) << 2;
  for (int n0 = 0; n0 < 1024; n0 += 16) {
    bf16x4 vv = *(const bf16x4*)(V + base + (size_t)(n0 + vrow) * 1024 + vcs);
    __syncthreads();   // previous chunk's Vs reads complete
    Vs[vrow][vcs + 0] = (float)vv[0];
    Vs[vrow][vcs + 1] = (float)vv[1];
    Vs[vrow][vcs + 2] = (float)vv[2];
    Vs[vrow][vcs + 3] = (float)vv[3];
    __syncthreads();
    #pragma unroll
    for (int nn0 = 0; nn0 < 4; ++nn0) {
      const int nn = nq + (nn0 << 2);
      float o = 0.f;
      #pragma unroll
      for (int e4 = 0; e4 < 16; ++e4) {
        f32x4 v4 = *(const f32x4*)&Vs[nn][e4 << 2];   // broadcast read
        o += v4[0]*ar[e4*4+0] + v4[1]*ar[e4*4+1] + v4[2]*ar[e4*4+2] + v4[3]*ar[e4*4+3];
      }
      OP[base + (size_t)(n0 + nn) * 1024 + d] = (__bf16)o;
    }
  }
}

extern "C" void kernel_launch(void* const* d_in, const int* in_sizes, int n_in,
                              void* d_out, int out_size, void* d_ws, size_t ws_size,
                              hipStream_t stream)
{
  const float* query = (const float*)d_in[0];
  const float* key   = (const float*)d_in[1];
  const float* value = (const float*)d_in[2];
  const float* keype = (const float*)d_in[3];
  const float* Wq    = (const float*)d_in[4];
  const float* Wk    = (const float*)d_in[5];
  const float* Wv    = (const float*)d_in[6];
  const float* Wo    = (const float*)d_in[7];
  float* out = (float*)d_out;

  const int M = 32 * 1024, N = 1024, K = 1024;
  const size_t elems = (size_t)M * N;

  // ws layout (bf16): Q | K' (k + pe) | V | out_pre   = 4 * 64 MB = 256 MB
  __bf16* Qp  = (__bf16*)d_ws;
  __bf16* Kpp = Qp  + elems;
  __bf16* Vp  = Kpp + elems;
  __bf16* OPp = Vp  + elems;

  dim3 blk(256, 1, 1);
  dim3 grd((M / 128) * (N / 128), 1, 1);   // 2048 blocks, n-tile fastest (L2 A-panel reuse)

  gemm_bt<true,  true,  false><<<grd, blk, 0, stream>>>(query, Wq, Qp,  nullptr, M, N, K);
  gemm_bt<true,  true,  true ><<<grd, blk, 0, stream>>>(key,   Wk, Kpp, keype,  M, N, K);
  gemm_bt<true,  true,  false><<<grd, blk, 0, stream>>>(value, Wv, Vp,  nullptr, M, N, K);
  attn_out_kernel<<<dim3(512, 1, 1), blk, 0, stream>>>(Qp, Kpp, Vp, OPp);
  gemm_bt<false, false, false><<<grd, blk, 0, stream>>>(OPp, Wo, out, nullptr, M, N, K);
}